// Round 6
// baseline (2602.311 us; speedup 1.0000x reference)
//
#include <hip/hip_runtime.h>
#include <hip/hip_bf16.h>

#define BQ 8192
#define CHUNK 2048
#define NCHUNK 4
typedef __attribute__((ext_vector_type(8))) __bf16 bf16x8;
typedef __attribute__((ext_vector_type(4))) float f32x4;
typedef __attribute__((ext_vector_type(4))) int int4v;

__device__ __forceinline__ f32x4 mfma16(bf16x8 a, bf16x8 b, f32x4 c) {
    return __builtin_amdgcn_mfma_f32_16x16x32_bf16(a, b, c, 0, 0, 0);
}

// 3-way bf16 split of an fp32 value: v ~= s0+s1+s2 to ~2^-25 rel.
__device__ __forceinline__ void split3(float v, __hip_bfloat16& s0,
                                       __hip_bfloat16& s1, __hip_bfloat16& s2) {
    s0 = __float2bfloat16(v);
    float r = v - __bfloat162float(s0);
    s1 = __float2bfloat16(r);
    r -= __bfloat162float(s1);
    s2 = __float2bfloat16(r);
}

// plane-pair schedule for 6-term fp32-emulated product, grouped by A-plane so
// conv kernels can skip xs re-staging: (a,w) = (0,0),(0,1),(0,2),(1,0),(1,1),(2,0)
__device__ __forceinline__ int pair_a(int pp) { return (0x211000 >> (4 * pp)) & 0xF; }
__device__ __forceinline__ int pair_w(int pp) { return (0x010210 >> (4 * pp)) & 0xF; }

// ---------------- prep kernels ----------------

__global__ void prep_scalars_k(
    const float* __restrict__ c1b, const float* __restrict__ g1,
    const float* __restrict__ b1,  const float* __restrict__ m1,
    const float* __restrict__ v1,
    const float* __restrict__ c2b, const float* __restrict__ g2,
    const float* __restrict__ b2,  const float* __restrict__ m2,
    const float* __restrict__ v2,
    const float* __restrict__ c3b, const float* __restrict__ g3,
    const float* __restrict__ b3,  const float* __restrict__ m3,
    const float* __restrict__ v3,
    const float* __restrict__ pfb, const float* __restrict__ vfb,
    const float* __restrict__ mfb,
    float* __restrict__ scale1, float* __restrict__ bias1f,
    float* __restrict__ scale2, float* __restrict__ bias2f,
    float* __restrict__ scale3, float* __restrict__ bias3f,
    float* __restrict__ biasfc)
{
    int t = threadIdx.x;  // 768 threads
    if (t < 64) {
        float s = g1[t] * rsqrtf(v1[t] + 1e-5f);
        scale1[t] = s;
        bias1f[t] = (c1b[t] - m1[t]) * s + b1[t];
    }
    if (t < 128) {
        float s2 = g2[t] * rsqrtf(v2[t] + 1e-5f);
        scale2[t] = s2;
        bias2f[t] = (c2b[t] - m2[t]) * s2 + b2[t];
        float s3 = g3[t] * rsqrtf(v3[t] + 1e-5f);
        scale3[t] = s3;
        bias3f[t] = (c3b[t] - m3[t]) * s3 + b3[t];
    }
    if (t < 256)      biasfc[t] = pfb[t];
    else if (t < 512) biasfc[t] = vfb[t - 256];
    else              biasfc[t] = mfb[t - 512];
}

// conv weights (O, CIN, 3, 3) fp32 -> 3 bf16 planes, slice-major [kt][n][kk], k = s*CIN + i
template<int CIN>
__global__ void prep_convw_k(const float* __restrict__ w,
                             __hip_bfloat16* __restrict__ wt, size_t planeW)
{
    int id = blockIdx.x * 256 + threadIdx.x;
    int kk = id & 31;
    int n  = (id >> 5) & 127;
    int kt = id >> 12;
    int k  = kt * 32 + kk;
    int s  = k / CIN;
    int i  = k & (CIN - 1);
    __hip_bfloat16 s0, s1, s2;
    split3(w[(n * CIN + i) * 9 + s], s0, s1, s2);
    wt[id] = s0; wt[id + planeW] = s1; wt[id + 2 * planeW] = s2;
}

// fused FC1 weight -> 3 bf16 planes: [kt 0..143][n 0..767][kk]; k' = p*128+c ; orig k = c*36+p
__global__ void prep_bigw_k(const float* __restrict__ pw,
                            const float* __restrict__ vw,
                            const float* __restrict__ mw,
                            __hip_bfloat16* __restrict__ bigw, size_t planeBW)
{
    int id = blockIdx.x * 256 + threadIdx.x;   // < 4608*768
    int kk = id & 31;
    int n  = (id >> 5) % 768;
    int kt = id / (32 * 768);
    int k2 = kt * 32 + kk;
    int c  = k2 & 127, p = k2 >> 7;
    int k  = c * 36 + p;
    float v;
    if (n < 256)      v = pw[n * 4608 + k];
    else if (n < 512) v = vw[(n - 256) * 4608 + k];
    else              v = mw[(n - 512) * 4644 + k];
    __hip_bfloat16 s0, s1, s2;
    split3(v, s0, s1, s2);
    bigw[id] = s0; bigw[id + planeBW] = s1; bigw[id + 2 * planeBW] = s2;
}

__global__ void prep_selw_k(const float* __restrict__ mw,
                            float* __restrict__ selw)
{
    int j = blockIdx.x, d = threadIdx.x;
    selw[j * 256 + d] = mw[d * 4644 + 4608 + j];
}

// ---------------- conv1 (4->64, K=36): exact fp32 VALU, split-stored ----------------

__global__ __launch_bounds__(256)
void conv1_k(const float* __restrict__ x,               // (B,4,36) full
             const float* __restrict__ w,               // (64,4,9)
             const float* __restrict__ scale, const float* __restrict__ biasf,
             __hip_bfloat16* __restrict__ out, size_t planeA,  // 3 planes (CHUNK,36,64)
             int b_base)
{
    __shared__ float wl[64 * 37];
    int tid = threadIdx.x;
    for (int c = tid; c < 64 * 36; c += 256) {
        int o = c / 36, k = c - o * 36;
        wl[o * 37 + k] = w[c];
    }
    __syncthreads();
    unsigned gid = blockIdx.x * 256 + tid;  // local (chunk) b*36*64 range
    int o = gid & 63;
    unsigned bp = gid >> 6;                 // local b*36+p
    unsigned b = bp / 36;
    int p = bp - b * 36;
    int py = p / 6, px = p - py * 6;
    const float* xb = x + (size_t)(b_base + b) * 4 * 36;
    float acc = 0.f;
#pragma unroll
    for (int i = 0; i < 4; ++i) {
#pragma unroll
        for (int s = 0; s < 9; ++s) {
            int ny = py + s / 3 - 1, nx = px + s % 3 - 1;
            if ((unsigned)ny < 6u && (unsigned)nx < 6u)
                acc += xb[i * 36 + ny * 6 + nx] * wl[o * 37 + i * 9 + s];
        }
    }
    float v = fmaxf(acc * scale[o] + biasf[o], 0.f);
    __hip_bfloat16 s0, s1, s2;
    split3(v, s0, s1, s2);
    size_t idx = (size_t)bp * 64 + o;
    out[idx] = s0; out[idx + planeA] = s1; out[idx + 2 * planeA] = s2;
}

// ---------------- conv2/conv3: implicit-im2col MFMA GEMM, 6-term fp32-emulated ----------------
// Block = 8 images (288 rows) x 128 cols; 4 waves in 2x2: wave tile 144r x 64c
// (9 row-tiles, acc[9][4]). A (xs) LDS-resident, staged 3x/kernel; B (weights)
// streamed global->register per kt with next-kt prefetch. NO barriers in K-loop.
template<int CIN>
__global__ __launch_bounds__(256, 2)
void conv_gemm_k(const __hip_bfloat16* __restrict__ in, size_t planeA,   // 3 planes (CHUNK,36,CIN)
                 const __hip_bfloat16* __restrict__ wt, size_t planeW,   // 3 planes [K/32][128][32]
                 const float* __restrict__ scale,
                 const float* __restrict__ biasf,
                 __hip_bfloat16* __restrict__ out, size_t planeO)        // 3 planes (CHUNK,36,128)
{
    constexpr int IMGS = 8;
    constexpr int ROWS = IMGS * 36;          // 288
    constexpr int PS   = CIN + 8;            // padded pixel stride (elems)
    constexpr int CPB  = CIN / 32;
    constexpr int NSLICE = CPB * 9;
    constexpr int XS_ELEMS = ROWS * PS;
    constexpr int CHPP = CIN / 8;            // 16B chunks per pixel
    __shared__ __align__(16) __hip_bfloat16 smem[XS_ELEMS + CIN];  // xs + zero region

    const int tid  = threadIdx.x;
    const int wave = tid >> 6, lane = tid & 63;
    const int m16  = lane & 15, quad = lane >> 4;
    const int wr   = wave >> 1, wc = wave & 1;
    const int ncol = wc * 64;
    const int b0   = blockIdx.x * IMGS;      // local image index

    if (tid < CIN) smem[XS_ELEMS + tid] = __float2bfloat16(0.f);

    f32x4 acc[9][4];
#pragma unroll
    for (int i = 0; i < 9; ++i)
#pragma unroll
        for (int j = 0; j < 4; ++j) acc[i][j] = f32x4{0,0,0,0};

    for (int pp = 0; pp < 6; ++pp) {
        const __hip_bfloat16* inb = in + (size_t)pair_a(pp) * planeA + (size_t)b0 * 36 * CIN;
        const __hip_bfloat16* wP  = wt + (size_t)pair_w(pp) * planeW;
        const bool stage_x = (pp == 0) || (pair_a(pp) != pair_a(pp - 1));

        if (stage_x) {
            __syncthreads();   // waves done reading previous xs (also covers zs init on pp=0)
            for (int c = tid; c < ROWS * CHPP; c += 256) {
                int pix = c / CHPP;
                int off = (c - pix * CHPP) * 8;
                *(int4v*)(smem + pix * PS + off) = *(const int4v*)(inb + pix * CIN + off);
            }
            __syncthreads();
        }

        // register prefetch of B frags for kt=0
        bf16x8 bfn[4];
#pragma unroll
        for (int j = 0; j < 4; ++j)
            bfn[j] = *(const bf16x8*)(wP + (size_t)(ncol + j * 16 + m16) * 32 + quad * 8);

        for (int s = 0; s < 9; ++s) {
            const int dy = s / 3 - 1, dx = s % 3 - 1;
            int aoff[9];
#pragma unroll
            for (int i = 0; i < 9; ++i) {
                int m   = (wr * 9 + i) * 16 + m16;   // 0..287
                int img = m / 36;
                int p   = m - img * 36;
                int py  = p / 6, px = p - py * 6;
                int ny  = py + dy, nx = px + dx;
                bool ok = ((unsigned)ny < 6u) && ((unsigned)nx < 6u);
                int base = ok ? ((img * 36 + ny * 6 + nx) * PS) : XS_ELEMS;
                aoff[i] = base + quad * 8;
            }
            for (int c = 0; c < CPB; ++c) {
                const int kt = s * CPB + c;
                bf16x8 bf[4];
#pragma unroll
                for (int j = 0; j < 4; ++j) bf[j] = bfn[j];
                if (kt + 1 < NSLICE) {
#pragma unroll
                    for (int j = 0; j < 4; ++j)
                        bfn[j] = *(const bf16x8*)(wP + ((size_t)(kt + 1) * 128 + ncol + j * 16 + m16) * 32 + quad * 8);
                }
                const int coff = c * 32;
#pragma unroll
                for (int i = 0; i < 9; ++i) {
                    bf16x8 af = *(const bf16x8*)(smem + aoff[i] + coff);
#pragma unroll
                    for (int j = 0; j < 4; ++j)
                        acc[i][j] = mfma16(af, bf[j], acc[i][j]);
                }
            }
        }
    }

    // epilogue: fused BN scale/bias + relu, split-store 3 bf16 planes
#pragma unroll
    for (int j = 0; j < 4; ++j) {
        const int n = ncol + j * 16 + m16;
        const float sc = scale[n], bi = biasf[n];
#pragma unroll
        for (int i = 0; i < 9; ++i) {
            const int mrow = (wr * 9 + i) * 16 + quad * 4;
#pragma unroll
            for (int r = 0; r < 4; ++r) {
                float v = fmaxf(acc[i][j][r] * sc + bi, 0.f);
                __hip_bfloat16 s0, s1, s2;
                split3(v, s0, s1, s2);
                size_t idx = (size_t)(b0 * 36 + mrow + r) * 128 + n;
                out[idx] = s0; out[idx + planeO] = s1; out[idx + 2 * planeO] = s2;
            }
        }
    }
}

// ---------------- FC1 partial GEMM: one plane-pair per block ----------------
// grid = 6 pp x 6 nblk x 16 mblk = 576 blocks; partial[pp] (CHUNK,768) fp32

__global__ __launch_bounds__(256, 3)
void fc_partial_k(const __hip_bfloat16* __restrict__ A, size_t planeF,    // 3 planes (CHUNK,4608)
                  const __hip_bfloat16* __restrict__ Bw, size_t planeBW,  // 3 planes [144][768][32]
                  float* __restrict__ partial)                            // [6](CHUNK,768)
{
    __shared__ __align__(16) __hip_bfloat16 smem[128 * 40 * 2];
    __hip_bfloat16* as = smem;
    __hip_bfloat16* bs = smem + 128 * 40;
    const int tid = threadIdx.x, wave = tid >> 6, lane = tid & 63;
    const int m16 = lane & 15, quad = lane >> 4;
    const int mblk = blockIdx.x & 15;
    const int rest = blockIdx.x >> 4;           // 0..35
    const int nblk = rest % 6;
    const int pp   = rest / 6;
    const size_t m0 = (size_t)mblk * 128;
    const int n0 = nblk * 128;
    const int wr = wave >> 1, wc = wave & 1;

    const __hip_bfloat16* Ap = A + (size_t)pair_a(pp) * planeF;
    const __hip_bfloat16* Bp = Bw + (size_t)pair_w(pp) * planeBW;

    f32x4 acc[4][4];
#pragma unroll
    for (int i = 0; i < 4; ++i)
#pragma unroll
        for (int j = 0; j < 4; ++j) acc[i][j] = f32x4{0,0,0,0};

    const int cr = tid >> 2, co = (tid & 3) * 8;
    int ao[4], bo[4];
#pragma unroll
    for (int i = 0; i < 4; ++i) {
        ao[i] = (wr * 64 + i * 16 + m16) * 40 + quad * 8;
        bo[i] = (wc * 64 + i * 16 + m16) * 40 + quad * 8;
    }

    auto ldA = [&](int kt, int4v& a0, int4v& a1) {
        const __hip_bfloat16* base = Ap + (m0 + cr) * 4608 + kt * 32 + co;
        a0 = *(const int4v*)base;
        a1 = *(const int4v*)(base + (size_t)64 * 4608);
    };
    auto ldB = [&](int kt, int4v& b0, int4v& b1) {
        const int4v* g = (const int4v*)(Bp + ((size_t)kt * 768 + n0) * 32);
        b0 = g[tid]; b1 = g[tid + 256];
    };
    auto stAB = [&](int4v a0, int4v a1, int4v b0, int4v b1) {
        *(int4v*)(as + cr * 40 + co) = a0;
        *(int4v*)(as + (cr + 64) * 40 + co) = a1;
        *(int4v*)(bs + cr * 40 + co) = b0;
        *(int4v*)(bs + (cr + 64) * 40 + co) = b1;
    };

    { int4v a0,a1,b0,b1; ldA(0,a0,a1); ldB(0,b0,b1); stAB(a0,a1,b0,b1); }
    __syncthreads();

    for (int kt = 0; kt < 144; ++kt) {
        int4v a0, a1, b0, b1;
        const bool more = (kt < 143);
        if (more) { ldA(kt + 1, a0, a1); ldB(kt + 1, b0, b1); }
        bf16x8 af[4], bf[4];
#pragma unroll
        for (int i = 0; i < 4; ++i) {
            af[i] = *(const bf16x8*)(as + ao[i]);
            bf[i] = *(const bf16x8*)(bs + bo[i]);
        }
#pragma unroll
        for (int i = 0; i < 4; ++i)
#pragma unroll
            for (int j = 0; j < 4; ++j)
                acc[i][j] = mfma16(af[i], bf[j], acc[i][j]);
        __syncthreads();
        if (more) { stAB(a0, a1, b0, b1); __syncthreads(); }
    }

    float* outp = partial + (size_t)pp * CHUNK * 768;
#pragma unroll
    for (int i = 0; i < 4; ++i) {
        const int row = wr * 64 + i * 16 + quad * 4;
#pragma unroll
        for (int j = 0; j < 4; ++j) {
            const int col = n0 + wc * 64 + j * 16 + m16;
#pragma unroll
            for (int r = 0; r < 4; ++r)
                outp[(m0 + row + r) * 768 + col] = acc[i][j][r];
        }
    }
}

// sum 6 partials + bias -> fc1o (deterministic, float4-vectorized)
__global__ __launch_bounds__(256)
void fc_reduce_k(const float* __restrict__ partial,   // [6](CHUNK,768)
                 const float* __restrict__ bias,      // 768
                 float* __restrict__ out)             // (CHUNK,768)
{
    int id = blockIdx.x * 256 + threadIdx.x;   // over CHUNK*192
    int c4 = id % 192, m = id / 192;
    f32x4 s = *(const f32x4*)(bias + c4 * 4);
#pragma unroll
    for (int pp = 0; pp < 6; ++pp)
        s += *(const f32x4*)(partial + ((size_t)pp * CHUNK + m) * 768 + c4 * 4);
    *(f32x4*)(out + (size_t)m * 768 + c4 * 4) = s;
}

// ---------------- heads: LN + small GEMVs + argmax + dueling combine (fp32) ----------------

__global__ __launch_bounds__(256)
void heads_k(const float* __restrict__ fc1o,            // (CHUNK,768): [piece|value|move]
             const float* __restrict__ pln_g, const float* __restrict__ pln_b,
             const float* __restrict__ pfc2_w, const float* __restrict__ pfc2_b,
             const float* __restrict__ mln_g, const float* __restrict__ mln_b,
             const float* __restrict__ mfc2_w, const float* __restrict__ mfc2_b,
             const float* __restrict__ vln_g, const float* __restrict__ vln_b,
             const float* __restrict__ vfc2_w, const float* __restrict__ vfc2_b,
             const float* __restrict__ selw,            // (36,256)
             float* __restrict__ q,                     // (B,1296) full
             int b_base)
{
    __shared__ float hp[256], hv[256], hm[256];
    __shared__ float pl[36], ml[36];
    __shared__ float red[4];
    __shared__ float valv, plm_s, mlm_s;
    __shared__ int amax_s;

    const int tid = threadIdx.x, wave = tid >> 6, lane = tid & 63;
    const size_t b = blockIdx.x;                // local
    const size_t bg = b_base + b;               // global
    const float* row = fc1o + b * 768;
    float pp = row[tid], vv = row[256 + tid], mm = row[512 + tid];

    auto warpSum = [&](float v) {
        v += __shfl_xor(v, 1);  v += __shfl_xor(v, 2);  v += __shfl_xor(v, 4);
        v += __shfl_xor(v, 8);  v += __shfl_xor(v, 16); v += __shfl_xor(v, 32);
        return v;
    };
    auto blockSum = [&](float v) {
        v = warpSum(v);
        if (lane == 0) red[wave] = v;
        __syncthreads();
        float s = red[0] + red[1] + red[2] + red[3];
        __syncthreads();
        return s;
    };
    auto lnrelu = [&](float x, const float* g, const float* bb) {
        float mu  = blockSum(x) * (1.f / 256.f);
        float d   = x - mu;
        float var = blockSum(d * d) * (1.f / 256.f);
        float y   = d * rsqrtf(var + 1e-5f) * g[tid] + bb[tid];
        return fmaxf(y, 0.f);
    };

    hp[tid] = lnrelu(pp, pln_g, pln_b);
    hv[tid] = lnrelu(vv, vln_g, vln_b);
    __syncthreads();

    {
        float h0 = hp[lane], h1 = hp[64 + lane], h2 = hp[128 + lane], h3 = hp[192 + lane];
#pragma unroll
        for (int jj = 0; jj < 9; ++jj) {
            int j = wave * 9 + jj;
            const float* wr_ = pfc2_w + j * 256;
            float s = h0 * wr_[lane] + h1 * wr_[64 + lane]
                    + h2 * wr_[128 + lane] + h3 * wr_[192 + lane];
            s = warpSum(s);
            if (lane == 0) pl[j] = s + pfc2_b[j];
        }
        if (wave == 0) {
            float g0 = hv[lane], g1 = hv[64 + lane], g2 = hv[128 + lane], g3 = hv[192 + lane];
            float s = g0 * vfc2_w[lane] + g1 * vfc2_w[64 + lane]
                    + g2 * vfc2_w[128 + lane] + g3 * vfc2_w[192 + lane];
            s = warpSum(s);
            if (lane == 0) valv = s + vfc2_b[0];
        }
    }
    __syncthreads();
    if (tid == 0) {   // first-max argmax (jnp semantics) + mean
        float m = -1e30f, s = 0.f; int idx = 0;
        for (int j = 0; j < 36; ++j) { float v = pl[j]; s += v; if (v > m) { m = v; idx = j; } }
        plm_s = s * (1.f / 36.f); amax_s = idx;
    }
    __syncthreads();

    mm += selw[amax_s * 256 + tid];   // one-hot concat == single column add
    hm[tid] = lnrelu(mm, mln_g, mln_b);
    __syncthreads();
    {
        float h0 = hm[lane], h1 = hm[64 + lane], h2 = hm[128 + lane], h3 = hm[192 + lane];
#pragma unroll
        for (int jj = 0; jj < 9; ++jj) {
            int j = wave * 9 + jj;
            const float* wr_ = mfc2_w + j * 256;
            float s = h0 * wr_[lane] + h1 * wr_[64 + lane]
                    + h2 * wr_[128 + lane] + h3 * wr_[192 + lane];
            s = warpSum(s);
            if (lane == 0) ml[j] = s + mfc2_b[j];
        }
    }
    __syncthreads();
    if (tid == 0) {
        float s = 0.f;
        for (int j = 0; j < 36; ++j) s += ml[j];
        mlm_s = s * (1.f / 36.f);
    }
    __syncthreads();

    const float val = valv, plm = plm_s, mlm = mlm_s;
    for (int idx = tid; idx < 1296; idx += 256) {
        int i = idx / 36, j = idx - i * 36;
        q[bg * 1296 + idx] = val + (pl[i] - plm) + (ml[j] - mlm);
    }
}

// ---------------- launch ----------------

extern "C" void kernel_launch(void* const* d_in, const int* in_sizes, int n_in,
                              void* d_out, int out_size, void* d_ws, size_t ws_size,
                              hipStream_t stream)
{
    const float* x       = (const float*)d_in[0];
    const float* conv1_w = (const float*)d_in[1];
    const float* conv1_b = (const float*)d_in[2];
    const float* bn1_g   = (const float*)d_in[3];
    const float* bn1_b   = (const float*)d_in[4];
    const float* bn1_m   = (const float*)d_in[5];
    const float* bn1_v   = (const float*)d_in[6];
    const float* conv2_w = (const float*)d_in[7];
    const float* conv2_b = (const float*)d_in[8];
    const float* bn2_g   = (const float*)d_in[9];
    const float* bn2_b   = (const float*)d_in[10];
    const float* bn2_m   = (const float*)d_in[11];
    const float* bn2_v   = (const float*)d_in[12];
    const float* conv3_w = (const float*)d_in[13];
    const float* conv3_b = (const float*)d_in[14];
    const float* bn3_g   = (const float*)d_in[15];
    const float* bn3_b   = (const float*)d_in[16];
    const float* bn3_m   = (const float*)d_in[17];
    const float* bn3_v   = (const float*)d_in[18];
    const float* pfc1_w  = (const float*)d_in[19];
    const float* pfc1_b  = (const float*)d_in[20];
    const float* pln_g   = (const float*)d_in[21];
    const float* pln_b   = (const float*)d_in[22];
    const float* pfc2_w  = (const float*)d_in[23];
    const float* pfc2_b  = (const float*)d_in[24];
    const float* mfc1_w  = (const float*)d_in[25];
    const float* mfc1_b  = (const float*)d_in[26];
    const float* mln_g   = (const float*)d_in[27];
    const float* mln_b   = (const float*)d_in[28];
    const float* mfc2_w  = (const float*)d_in[29];
    const float* mfc2_b  = (const float*)d_in[30];
    const float* vfc1_w  = (const float*)d_in[31];
    const float* vfc1_b  = (const float*)d_in[32];
    const float* vln_g   = (const float*)d_in[33];
    const float* vln_b   = (const float*)d_in[34];
    const float* vfc2_w  = (const float*)d_in[35];
    const float* vfc2_b  = (const float*)d_in[36];

    const size_t planeW2 = 576 * 128;               // conv2 weight plane elems
    const size_t planeW3 = 1152 * 128;              // conv3 weight plane elems
    const size_t planeBW = (size_t)4608 * 768;      // fc weight plane elems
    const size_t planeA1 = (size_t)CHUNK * 36 * 64; // h1 plane elems (per chunk)
    const size_t planeA2 = (size_t)CHUNK * 36 * 128;// h2/h3 plane elems (per chunk)

    char* ws = (char*)d_ws;
    size_t off = 0;
    auto alloc = [&](size_t bytes) -> char* {
        char* p = ws + off; off += (bytes + 255) & ~(size_t)255; return p;
    };
    __hip_bfloat16* w2t  = (__hip_bfloat16*)alloc(3 * planeW2 * 2);
    __hip_bfloat16* w3t  = (__hip_bfloat16*)alloc(3 * planeW3 * 2);
    __hip_bfloat16* bigw = (__hip_bfloat16*)alloc(3 * planeBW * 2);
    float* selw   = (float*)alloc(36 * 256 * 4);
    float* scale1 = (float*)alloc(64 * 4);
    float* bias1f = (float*)alloc(64 * 4);
    float* scale2 = (float*)alloc(128 * 4);
    float* bias2f = (float*)alloc(128 * 4);
    float* scale3 = (float*)alloc(128 * 4);
    float* bias3f = (float*)alloc(128 * 4);
    float* biasfc = (float*)alloc(768 * 4);
    // ping-pong arenas, per-chunk:
    //   A1: h1 (28.3MB) -> h3 (56.6MB)
    //   A2: h2 (56.6MB) -> { fc1o (6.3MB) @+0, fc partials (37.75MB) @+8MB }
    char* A1 = alloc(3 * planeA2 * 2);   // 56.6 MB
    char* A2 = alloc(3 * planeA2 * 2);   // 56.6 MB
    // total ws ~136 MB (round-2 proved >=196 MB available)

    prep_scalars_k<<<1, 768, 0, stream>>>(
        conv1_b, bn1_g, bn1_b, bn1_m, bn1_v,
        conv2_b, bn2_g, bn2_b, bn2_m, bn2_v,
        conv3_b, bn3_g, bn3_b, bn3_m, bn3_v,
        pfc1_b, vfc1_b, mfc1_b,
        scale1, bias1f, scale2, bias2f, scale3, bias3f, biasfc);
    prep_convw_k<64><<<288, 256, 0, stream>>>(conv2_w, w2t, planeW2);
    prep_convw_k<128><<<576, 256, 0, stream>>>(conv3_w, w3t, planeW3);
    prep_bigw_k<<<13824, 256, 0, stream>>>(pfc1_w, vfc1_w, mfc1_w, bigw, planeBW);
    prep_selw_k<<<36, 256, 0, stream>>>(mfc1_w, selw);

    __hip_bfloat16* h1s  = (__hip_bfloat16*)A1;
    __hip_bfloat16* h2s  = (__hip_bfloat16*)A2;
    __hip_bfloat16* h3s  = (__hip_bfloat16*)A1;            // overwrites h1s (dead after conv2)
    float*          fc1o = (float*)A2;                     // overwrites h2s (dead after conv3)
    float*          fpar = (float*)(A2 + (8u << 20));      // 37.75MB partials after fc1o

    for (int cchunk = 0; cchunk < NCHUNK; ++cchunk) {
        const int b_base = cchunk * CHUNK;
        conv1_k<<<CHUNK * 36 * 64 / 256, 256, 0, stream>>>(
            x, conv1_w, scale1, bias1f, h1s, planeA1, b_base);
        conv_gemm_k<64><<<CHUNK / 8, 256, 0, stream>>>(
            h1s, planeA1, w2t, planeW2, scale2, bias2f, h2s, planeA2);
        conv_gemm_k<128><<<CHUNK / 8, 256, 0, stream>>>(
            h2s, planeA2, w3t, planeW3, scale3, bias3f, h3s, planeA2);
        fc_partial_k<<<576, 256, 0, stream>>>(h3s, planeA2, bigw, planeBW, fpar);
        fc_reduce_k<<<CHUNK * 192 / 256, 256, 0, stream>>>(fpar, biasfc, fc1o);
        heads_k<<<CHUNK, 256, 0, stream>>>(fc1o,
            pln_g, pln_b, pfc2_w, pfc2_b,
            mln_g, mln_b, mfc2_w, mfc2_b,
            vln_g, vln_b, vfc2_w, vfc2_b,
            selw, (float*)d_out, b_base);
    }
}

// Round 7
// 2078.360 us; speedup vs baseline: 1.2521x; 1.2521x over previous
//
#include <hip/hip_runtime.h>
#include <hip/hip_bf16.h>

#define BQ 8192
#define CHUNK 2048
#define NCHUNK 4
typedef __attribute__((ext_vector_type(8))) __bf16 bf16x8;
typedef __attribute__((ext_vector_type(4))) float f32x4;
typedef __attribute__((ext_vector_type(4))) int int4v;

__device__ __forceinline__ f32x4 mfma16(bf16x8 a, bf16x8 b, f32x4 c) {
    return __builtin_amdgcn_mfma_f32_16x16x32_bf16(a, b, c, 0, 0, 0);
}

// 3-way bf16 split of an fp32 value: v ~= s0+s1+s2 to ~2^-25 rel.
__device__ __forceinline__ void split3(float v, __hip_bfloat16& s0,
                                       __hip_bfloat16& s1, __hip_bfloat16& s2) {
    s0 = __float2bfloat16(v);
    float r = v - __bfloat162float(s0);
    s1 = __float2bfloat16(r);
    r -= __bfloat162float(s1);
    s2 = __float2bfloat16(r);
}

// plane-pair schedule for 6-term fp32-emulated product, grouped by A-plane so
// conv kernels can skip xs re-staging: (a,w) = (0,0),(0,1),(0,2),(1,0),(1,1),(2,0)
__device__ __forceinline__ int pair_a(int pp) { return (0x211000 >> (4 * pp)) & 0xF; }
__device__ __forceinline__ int pair_w(int pp) { return (0x010210 >> (4 * pp)) & 0xF; }

// ---------------- prep kernels ----------------

__global__ void prep_scalars_k(
    const float* __restrict__ c1b, const float* __restrict__ g1,
    const float* __restrict__ b1,  const float* __restrict__ m1,
    const float* __restrict__ v1,
    const float* __restrict__ c2b, const float* __restrict__ g2,
    const float* __restrict__ b2,  const float* __restrict__ m2,
    const float* __restrict__ v2,
    const float* __restrict__ c3b, const float* __restrict__ g3,
    const float* __restrict__ b3,  const float* __restrict__ m3,
    const float* __restrict__ v3,
    const float* __restrict__ pfb, const float* __restrict__ vfb,
    const float* __restrict__ mfb,
    float* __restrict__ scale1, float* __restrict__ bias1f,
    float* __restrict__ scale2, float* __restrict__ bias2f,
    float* __restrict__ scale3, float* __restrict__ bias3f,
    float* __restrict__ biasfc)
{
    int t = threadIdx.x;  // 768 threads
    if (t < 64) {
        float s = g1[t] * rsqrtf(v1[t] + 1e-5f);
        scale1[t] = s;
        bias1f[t] = (c1b[t] - m1[t]) * s + b1[t];
    }
    if (t < 128) {
        float s2 = g2[t] * rsqrtf(v2[t] + 1e-5f);
        scale2[t] = s2;
        bias2f[t] = (c2b[t] - m2[t]) * s2 + b2[t];
        float s3 = g3[t] * rsqrtf(v3[t] + 1e-5f);
        scale3[t] = s3;
        bias3f[t] = (c3b[t] - m3[t]) * s3 + b3[t];
    }
    if (t < 256)      biasfc[t] = pfb[t];
    else if (t < 512) biasfc[t] = vfb[t - 256];
    else              biasfc[t] = mfb[t - 512];
}

// conv weights (O, CIN, 3, 3) fp32 -> 3 bf16 planes, slice-major [kt][n][kk], k = s*CIN + i
template<int CIN>
__global__ void prep_convw_k(const float* __restrict__ w,
                             __hip_bfloat16* __restrict__ wt, size_t planeW)
{
    int id = blockIdx.x * 256 + threadIdx.x;
    int kk = id & 31;
    int n  = (id >> 5) & 127;
    int kt = id >> 12;
    int k  = kt * 32 + kk;
    int s  = k / CIN;
    int i  = k & (CIN - 1);
    __hip_bfloat16 s0, s1, s2;
    split3(w[(n * CIN + i) * 9 + s], s0, s1, s2);
    wt[id] = s0; wt[id + planeW] = s1; wt[id + 2 * planeW] = s2;
}

// fused FC1 weight -> 3 bf16 planes: [kt 0..143][n 0..767][kk]; k' = p*128+c ; orig k = c*36+p
__global__ void prep_bigw_k(const float* __restrict__ pw,
                            const float* __restrict__ vw,
                            const float* __restrict__ mw,
                            __hip_bfloat16* __restrict__ bigw, size_t planeBW)
{
    int id = blockIdx.x * 256 + threadIdx.x;   // < 4608*768
    int kk = id & 31;
    int n  = (id >> 5) % 768;
    int kt = id / (32 * 768);
    int k2 = kt * 32 + kk;
    int c  = k2 & 127, p = k2 >> 7;
    int k  = c * 36 + p;
    float v;
    if (n < 256)      v = pw[n * 4608 + k];
    else if (n < 512) v = vw[(n - 256) * 4608 + k];
    else              v = mw[(n - 512) * 4644 + k];
    __hip_bfloat16 s0, s1, s2;
    split3(v, s0, s1, s2);
    bigw[id] = s0; bigw[id + planeBW] = s1; bigw[id + 2 * planeBW] = s2;
}

__global__ void prep_selw_k(const float* __restrict__ mw,
                            float* __restrict__ selw)
{
    int j = blockIdx.x, d = threadIdx.x;
    selw[j * 256 + d] = mw[d * 4644 + 4608 + j];
}

// ---------------- conv1 (4->64, K=36): exact fp32 VALU, split-stored ----------------

__global__ __launch_bounds__(256)
void conv1_k(const float* __restrict__ x,               // (B,4,36) full
             const float* __restrict__ w,               // (64,4,9)
             const float* __restrict__ scale, const float* __restrict__ biasf,
             __hip_bfloat16* __restrict__ out, size_t planeA,  // 3 planes (CHUNK,36,64)
             int b_base)
{
    __shared__ float wl[64 * 37];
    int tid = threadIdx.x;
    for (int c = tid; c < 64 * 36; c += 256) {
        int o = c / 36, k = c - o * 36;
        wl[o * 37 + k] = w[c];
    }
    __syncthreads();
    unsigned gid = blockIdx.x * 256 + tid;  // local (chunk) b*36*64 range
    int o = gid & 63;
    unsigned bp = gid >> 6;                 // local b*36+p
    unsigned b = bp / 36;
    int p = bp - b * 36;
    int py = p / 6, px = p - py * 6;
    const float* xb = x + (size_t)(b_base + b) * 4 * 36;
    float acc = 0.f;
#pragma unroll
    for (int i = 0; i < 4; ++i) {
#pragma unroll
        for (int s = 0; s < 9; ++s) {
            int ny = py + s / 3 - 1, nx = px + s % 3 - 1;
            if ((unsigned)ny < 6u && (unsigned)nx < 6u)
                acc += xb[i * 36 + ny * 6 + nx] * wl[o * 37 + i * 9 + s];
        }
    }
    float v = fmaxf(acc * scale[o] + biasf[o], 0.f);
    __hip_bfloat16 s0, s1, s2;
    split3(v, s0, s1, s2);
    size_t idx = (size_t)bp * 64 + o;
    out[idx] = s0; out[idx + planeA] = s1; out[idx + 2 * planeA] = s2;
}

// ---------------- conv2/conv3: implicit-im2col MFMA GEMM, 6-term fp32-emulated ----------------
// Round-5 proven tile (4 images, 144x128, wave 144x32) + DOUBLE-BUFFERED weight
// LDS: one barrier per kt instead of two. acc persists over 6 plane-pairs;
// xs staged only on A-plane change (3 of 6 passes).
template<int CIN>
__global__ __launch_bounds__(256, 2)
void conv_gemm_k(const __hip_bfloat16* __restrict__ in, size_t planeA,   // 3 planes (CHUNK,36,CIN)
                 const __hip_bfloat16* __restrict__ wt, size_t planeW,   // 3 planes [K/32][128][32]
                 const float* __restrict__ scale,
                 const float* __restrict__ biasf,
                 __hip_bfloat16* __restrict__ out, size_t planeO)        // 3 planes (CHUNK,36,128)
{
    constexpr int PS  = CIN + 8;
    constexpr int CPB = CIN / 32;
    constexpr int NSLICE = CPB * 9;
    constexpr int XS_ELEMS = 144 * PS;
    constexpr int WBUF = 128 * 40;     // elems per weight buffer
    __shared__ __align__(16) __hip_bfloat16 smem[XS_ELEMS + 2 * WBUF + CIN];
    __hip_bfloat16* xs   = smem;
    __hip_bfloat16* wsld = smem + XS_ELEMS;             // 2 buffers
    __hip_bfloat16* zs   = smem + XS_ELEMS + 2 * WBUF;  // zero region (SAME-pad reads)

    const int tid  = threadIdx.x;
    const int wave = tid >> 6, lane = tid & 63;
    const int m16  = lane & 15, quad = lane >> 4;
    const int b0   = blockIdx.x * 4;   // local image index

    if (tid < CIN) zs[tid] = __float2bfloat16(0.f);

    f32x4 acc[9][2];
#pragma unroll
    for (int i = 0; i < 9; ++i) { acc[i][0] = f32x4{0,0,0,0}; acc[i][1] = f32x4{0,0,0,0}; }

    const int cbase = wave * 32;
    const int bo0 = (cbase + m16) * 40 + quad * 8;
    const int bo1 = (cbase + 16 + m16) * 40 + quad * 8;
    const int wwr = (tid >> 2) * 40 + (tid & 3) * 8;          // write offset chunk 0
    const int wwr2 = ((tid + 256) >> 2) * 40 + (tid & 3) * 8; // write offset chunk 1

    constexpr int CHPP = CIN / 8;
    for (int pp = 0; pp < 6; ++pp) {
        const __hip_bfloat16* inb = in + (size_t)pair_a(pp) * planeA + (size_t)b0 * 36 * CIN;
        const __hip_bfloat16* wP  = wt + (size_t)pair_w(pp) * planeW;
        const bool stage_x = (pp == 0) || (pair_a(pp) != pair_a(pp - 1));

        __syncthreads();   // previous pass finished all LDS reads (covers zs init at pp=0)
        if (stage_x) {
            for (int c = tid; c < 144 * CHPP; c += 256) {
                int pix = c / CHPP;
                int off = (c - pix * CHPP) * 8;
                *(int4v*)(xs + pix * PS + off) = *(const int4v*)(inb + pix * CIN + off);
            }
        }
        {   // stage weight slice kt=0 into buffer 0
            const int4v* g = (const int4v*)wP;
            int4v w0 = g[tid], w1 = g[tid + 256];
            *(int4v*)(wsld + wwr) = w0;
            *(int4v*)(wsld + wwr2) = w1;
        }
        __syncthreads();
        int cur = 0;

        for (int s = 0; s < 9; ++s) {
            const int dy = s / 3 - 1, dx = s % 3 - 1;
            int aoff[9];
#pragma unroll
            for (int rt = 0; rt < 9; ++rt) {
                int m   = rt * 16 + m16;          // 0..143
                int img = m / 36;
                int p   = m - img * 36;
                int py  = p / 6, px = p - py * 6;
                int ny  = py + dy, nx = px + dx;
                bool ok = ((unsigned)ny < 6u) && ((unsigned)nx < 6u);
                int base = ok ? ((img * 36 + ny * 6 + nx) * PS) : (XS_ELEMS + 2 * WBUF);
                aoff[rt] = base + quad * 8;
            }
            for (int c = 0; c < CPB; ++c) {
                const int kt = s * CPB + c;
                const bool more = (kt + 1 < NSLICE);
                int4v n0, n1;
                if (more) {  // global->reg prefetch of next weight slice
                    const int4v* g = (const int4v*)(wP + (size_t)(kt + 1) * 128 * 32);
                    n0 = g[tid]; n1 = g[tid + 256];
                }
                const __hip_bfloat16* wb = wsld + cur * WBUF;
                bf16x8 bf0 = *(const bf16x8*)(wb + bo0);
                bf16x8 bf1 = *(const bf16x8*)(wb + bo1);
                const int coff = c * 32;
#pragma unroll
                for (int rt = 0; rt < 9; ++rt) {
                    bf16x8 af = *(const bf16x8*)(smem + aoff[rt] + coff);
                    acc[rt][0] = mfma16(af, bf0, acc[rt][0]);
                    acc[rt][1] = mfma16(af, bf1, acc[rt][1]);
                }
                if (more) {  // write next slice into alternate buffer
                    __hip_bfloat16* wn = wsld + (cur ^ 1) * WBUF;
                    *(int4v*)(wn + wwr) = n0;
                    *(int4v*)(wn + wwr2) = n1;
                }
                __syncthreads();   // single barrier per kt (dbuf)
                cur ^= 1;
            }
        }
    }

    // epilogue: fused BN scale/bias + relu, split-store 3 bf16 planes
#pragma unroll
    for (int ct = 0; ct < 2; ++ct) {
        const int n = cbase + ct * 16 + m16;
        const float sc = scale[n], bi = biasf[n];
#pragma unroll
        for (int rt = 0; rt < 9; ++rt) {
            const int mrow = rt * 16 + quad * 4;
#pragma unroll
            for (int r = 0; r < 4; ++r) {
                float v = fmaxf(acc[rt][ct][r] * sc + bi, 0.f);
                __hip_bfloat16 s0, s1, s2;
                split3(v, s0, s1, s2);
                size_t idx = (size_t)(b0 * 36 + mrow + r) * 128 + n;
                out[idx] = s0; out[idx + planeO] = s1; out[idx + 2 * planeO] = s2;
            }
        }
    }
}

// ---------------- FC1 partial GEMM: one plane-pair per block, dbuf LDS ----------------
// grid = 6 pp x 6 nblk x 16 mblk = 576 blocks; partial[pp] (CHUNK,768) fp32

__global__ __launch_bounds__(256, 3)
void fc_partial_k(const __hip_bfloat16* __restrict__ A, size_t planeF,    // 3 planes (CHUNK,4608)
                  const __hip_bfloat16* __restrict__ Bw, size_t planeBW,  // 3 planes [144][768][32]
                  float* __restrict__ partial)                            // [6](CHUNK,768)
{
    constexpr int HBUF = 128 * 40;          // as or bs elems
    __shared__ __align__(16) __hip_bfloat16 smem[2 * 2 * HBUF];  // [buf][as|bs]
    const int tid = threadIdx.x, wave = tid >> 6, lane = tid & 63;
    const int m16 = lane & 15, quad = lane >> 4;
    const int mblk = blockIdx.x & 15;
    const int rest = blockIdx.x >> 4;           // 0..35
    const int nblk = rest % 6;
    const int pp   = rest / 6;
    const size_t m0 = (size_t)mblk * 128;
    const int n0 = nblk * 128;
    const int wr = wave >> 1, wc = wave & 1;

    const __hip_bfloat16* Ap = A + (size_t)pair_a(pp) * planeF;
    const __hip_bfloat16* Bp = Bw + (size_t)pair_w(pp) * planeBW;

    f32x4 acc[4][4];
#pragma unroll
    for (int i = 0; i < 4; ++i)
#pragma unroll
        for (int j = 0; j < 4; ++j) acc[i][j] = f32x4{0,0,0,0};

    const int cr = tid >> 2, co = (tid & 3) * 8;
    int ao[4], bo[4];
#pragma unroll
    for (int i = 0; i < 4; ++i) {
        ao[i] = (wr * 64 + i * 16 + m16) * 40 + quad * 8;           // into as
        bo[i] = HBUF + (wc * 64 + i * 16 + m16) * 40 + quad * 8;    // into bs
    }

    auto ldA = [&](int kt, int4v& a0, int4v& a1) {
        const __hip_bfloat16* base = Ap + (m0 + cr) * 4608 + kt * 32 + co;
        a0 = *(const int4v*)base;
        a1 = *(const int4v*)(base + (size_t)64 * 4608);
    };
    auto ldB = [&](int kt, int4v& b0, int4v& b1) {
        const int4v* g = (const int4v*)(Bp + ((size_t)kt * 768 + n0) * 32);
        b0 = g[tid]; b1 = g[tid + 256];
    };
    auto stAB = [&](int buf, int4v a0, int4v a1, int4v b0, int4v b1) {
        __hip_bfloat16* base = smem + buf * 2 * HBUF;
        *(int4v*)(base + cr * 40 + co) = a0;
        *(int4v*)(base + (cr + 64) * 40 + co) = a1;
        *(int4v*)(base + HBUF + cr * 40 + co) = b0;
        *(int4v*)(base + HBUF + (cr + 64) * 40 + co) = b1;
    };

    { int4v a0,a1,b0,b1; ldA(0,a0,a1); ldB(0,b0,b1); stAB(0,a0,a1,b0,b1); }
    __syncthreads();
    int cur = 0;

    for (int kt = 0; kt < 144; ++kt) {
        int4v a0, a1, b0, b1;
        const bool more = (kt < 143);
        if (more) { ldA(kt + 1, a0, a1); ldB(kt + 1, b0, b1); }
        const __hip_bfloat16* base = smem + cur * 2 * HBUF;
        bf16x8 af[4], bf[4];
#pragma unroll
        for (int i = 0; i < 4; ++i) {
            af[i] = *(const bf16x8*)(base + ao[i]);
            bf[i] = *(const bf16x8*)(base + bo[i]);
        }
#pragma unroll
        for (int i = 0; i < 4; ++i)
#pragma unroll
            for (int j = 0; j < 4; ++j)
                acc[i][j] = mfma16(af[i], bf[j], acc[i][j]);
        if (more) { stAB(cur ^ 1, a0, a1, b0, b1); }
        __syncthreads();   // single barrier per kt (dbuf)
        cur ^= 1;
    }

    float* outp = partial + (size_t)pp * CHUNK * 768;
#pragma unroll
    for (int i = 0; i < 4; ++i) {
        const int row = wr * 64 + i * 16 + quad * 4;
#pragma unroll
        for (int j = 0; j < 4; ++j) {
            const int col = n0 + wc * 64 + j * 16 + m16;
#pragma unroll
            for (int r = 0; r < 4; ++r)
                outp[(m0 + row + r) * 768 + col] = acc[i][j][r];
        }
    }
}

// ---------------- heads: partial-sum + LN + small GEMVs + argmax + dueling (fp32) ----------------

__global__ __launch_bounds__(256)
void heads_k(const float* __restrict__ partial,          // [6](CHUNK,768): [piece|value|move]
             const float* __restrict__ biasfc,           // 768
             const float* __restrict__ pln_g, const float* __restrict__ pln_b,
             const float* __restrict__ pfc2_w, const float* __restrict__ pfc2_b,
             const float* __restrict__ mln_g, const float* __restrict__ mln_b,
             const float* __restrict__ mfc2_w, const float* __restrict__ mfc2_b,
             const float* __restrict__ vln_g, const float* __restrict__ vln_b,
             const float* __restrict__ vfc2_w, const float* __restrict__ vfc2_b,
             const float* __restrict__ selw,             // (36,256)
             float* __restrict__ q,                      // (B,1296) full
             int b_base)
{
    __shared__ float hp[256], hv[256], hm[256];
    __shared__ float pl[36], ml[36];
    __shared__ float red[4];
    __shared__ float valv, plm_s, mlm_s;
    __shared__ int amax_s;

    const int tid = threadIdx.x, wave = tid >> 6, lane = tid & 63;
    const size_t b = blockIdx.x;                // local
    const size_t bg = b_base + b;               // global

    // inline fc-reduce: sum 6 partials + bias
    float pp = biasfc[tid], vv = biasfc[256 + tid], mm = biasfc[512 + tid];
#pragma unroll
    for (int k = 0; k < 6; ++k) {
        const float* row = partial + (size_t)k * CHUNK * 768 + b * 768;
        pp += row[tid]; vv += row[256 + tid]; mm += row[512 + tid];
    }

    auto warpSum = [&](float v) {
        v += __shfl_xor(v, 1);  v += __shfl_xor(v, 2);  v += __shfl_xor(v, 4);
        v += __shfl_xor(v, 8);  v += __shfl_xor(v, 16); v += __shfl_xor(v, 32);
        return v;
    };
    auto blockSum = [&](float v) {
        v = warpSum(v);
        if (lane == 0) red[wave] = v;
        __syncthreads();
        float s = red[0] + red[1] + red[2] + red[3];
        __syncthreads();
        return s;
    };
    auto lnrelu = [&](float x, const float* g, const float* bb) {
        float mu  = blockSum(x) * (1.f / 256.f);
        float d   = x - mu;
        float var = blockSum(d * d) * (1.f / 256.f);
        float y   = d * rsqrtf(var + 1e-5f) * g[tid] + bb[tid];
        return fmaxf(y, 0.f);
    };

    hp[tid] = lnrelu(pp, pln_g, pln_b);
    hv[tid] = lnrelu(vv, vln_g, vln_b);
    __syncthreads();

    {
        float h0 = hp[lane], h1 = hp[64 + lane], h2 = hp[128 + lane], h3 = hp[192 + lane];
#pragma unroll
        for (int jj = 0; jj < 9; ++jj) {
            int j = wave * 9 + jj;
            const float* wr_ = pfc2_w + j * 256;
            float s = h0 * wr_[lane] + h1 * wr_[64 + lane]
                    + h2 * wr_[128 + lane] + h3 * wr_[192 + lane];
            s = warpSum(s);
            if (lane == 0) pl[j] = s + pfc2_b[j];
        }
        if (wave == 0) {
            float g0 = hv[lane], g1 = hv[64 + lane], g2 = hv[128 + lane], g3 = hv[192 + lane];
            float s = g0 * vfc2_w[lane] + g1 * vfc2_w[64 + lane]
                    + g2 * vfc2_w[128 + lane] + g3 * vfc2_w[192 + lane];
            s = warpSum(s);
            if (lane == 0) valv = s + vfc2_b[0];
        }
    }
    __syncthreads();
    if (tid == 0) {   // first-max argmax (jnp semantics) + mean
        float m = -1e30f, s = 0.f; int idx = 0;
        for (int j = 0; j < 36; ++j) { float v = pl[j]; s += v; if (v > m) { m = v; idx = j; } }
        plm_s = s * (1.f / 36.f); amax_s = idx;
    }
    __syncthreads();

    mm += selw[amax_s * 256 + tid];   // one-hot concat == single column add
    hm[tid] = lnrelu(mm, mln_g, mln_b);
    __syncthreads();
    {
        float h0 = hm[lane], h1 = hm[64 + lane], h2 = hm[128 + lane], h3 = hm[192 + lane];
#pragma unroll
        for (int jj = 0; jj < 9; ++jj) {
            int j = wave * 9 + jj;
            const float* wr_ = mfc2_w + j * 256;
            float s = h0 * wr_[lane] + h1 * wr_[64 + lane]
                    + h2 * wr_[128 + lane] + h3 * wr_[192 + lane];
            s = warpSum(s);
            if (lane == 0) ml[j] = s + mfc2_b[j];
        }
    }
    __syncthreads();
    if (tid == 0) {
        float s = 0.f;
        for (int j = 0; j < 36; ++j) s += ml[j];
        mlm_s = s * (1.f / 36.f);
    }
    __syncthreads();

    const float val = valv, plm = plm_s, mlm = mlm_s;
    for (int idx = tid; idx < 1296; idx += 256) {
        int i = idx / 36, j = idx - i * 36;
        q[bg * 1296 + idx] = val + (pl[i] - plm) + (ml[j] - mlm);
    }
}

// ---------------- launch ----------------

extern "C" void kernel_launch(void* const* d_in, const int* in_sizes, int n_in,
                              void* d_out, int out_size, void* d_ws, size_t ws_size,
                              hipStream_t stream)
{
    const float* x       = (const float*)d_in[0];
    const float* conv1_w = (const float*)d_in[1];
    const float* conv1_b = (const float*)d_in[2];
    const float* bn1_g   = (const float*)d_in[3];
    const float* bn1_b   = (const float*)d_in[4];
    const float* bn1_m   = (const float*)d_in[5];
    const float* bn1_v   = (const float*)d_in[6];
    const float* conv2_w = (const float*)d_in[7];
    const float* conv2_b = (const float*)d_in[8];
    const float* bn2_g   = (const float*)d_in[9];
    const float* bn2_b   = (const float*)d_in[10];
    const float* bn2_m   = (const float*)d_in[11];
    const float* bn2_v   = (const float*)d_in[12];
    const float* conv3_w = (const float*)d_in[13];
    const float* conv3_b = (const float*)d_in[14];
    const float* bn3_g   = (const float*)d_in[15];
    const float* bn3_b   = (const float*)d_in[16];
    const float* bn3_m   = (const float*)d_in[17];
    const float* bn3_v   = (const float*)d_in[18];
    const float* pfc1_w  = (const float*)d_in[19];
    const float* pfc1_b  = (const float*)d_in[20];
    const float* pln_g   = (const float*)d_in[21];
    const float* pln_b   = (const float*)d_in[22];
    const float* pfc2_w  = (const float*)d_in[23];
    const float* pfc2_b  = (const float*)d_in[24];
    const float* mfc1_w  = (const float*)d_in[25];
    const float* mfc1_b  = (const float*)d_in[26];
    const float* mln_g   = (const float*)d_in[27];
    const float* mln_b   = (const float*)d_in[28];
    const float* mfc2_w  = (const float*)d_in[29];
    const float* mfc2_b  = (const float*)d_in[30];
    const float* vfc1_w  = (const float*)d_in[31];
    const float* vfc1_b  = (const float*)d_in[32];
    const float* vln_g   = (const float*)d_in[33];
    const float* vln_b   = (const float*)d_in[34];
    const float* vfc2_w  = (const float*)d_in[35];
    const float* vfc2_b  = (const float*)d_in[36];

    const size_t planeW2 = 576 * 128;               // conv2 weight plane elems
    const size_t planeW3 = 1152 * 128;              // conv3 weight plane elems
    const size_t planeBW = (size_t)4608 * 768;      // fc weight plane elems
    const size_t planeA1 = (size_t)CHUNK * 36 * 64; // h1 plane elems (per chunk)
    const size_t planeA2 = (size_t)CHUNK * 36 * 128;// h2/h3 plane elems (per chunk)

    char* ws = (char*)d_ws;
    size_t off = 0;
    auto alloc = [&](size_t bytes) -> char* {
        char* p = ws + off; off += (bytes + 255) & ~(size_t)255; return p;
    };
    __hip_bfloat16* w2t  = (__hip_bfloat16*)alloc(3 * planeW2 * 2);
    __hip_bfloat16* w3t  = (__hip_bfloat16*)alloc(3 * planeW3 * 2);
    __hip_bfloat16* bigw = (__hip_bfloat16*)alloc(3 * planeBW * 2);
    float* selw   = (float*)alloc(36 * 256 * 4);
    float* scale1 = (float*)alloc(64 * 4);
    float* bias1f = (float*)alloc(64 * 4);
    float* scale2 = (float*)alloc(128 * 4);
    float* bias2f = (float*)alloc(128 * 4);
    float* scale3 = (float*)alloc(128 * 4);
    float* bias3f = (float*)alloc(128 * 4);
    float* biasfc = (float*)alloc(768 * 4);
    // ping-pong arenas, per-chunk:
    //   A1: h1 (28.3MB) -> h3 (56.6MB)
    //   A2: h2 (56.6MB) -> fc partials (37.75MB)
    char* A1 = alloc(3 * planeA2 * 2);   // 56.6 MB
    char* A2 = alloc(3 * planeA2 * 2);   // 56.6 MB
    // total ws ~136 MB (round-2 proved >=196 MB available; round-3 crash proved <475)

    prep_scalars_k<<<1, 768, 0, stream>>>(
        conv1_b, bn1_g, bn1_b, bn1_m, bn1_v,
        conv2_b, bn2_g, bn2_b, bn2_m, bn2_v,
        conv3_b, bn3_g, bn3_b, bn3_m, bn3_v,
        pfc1_b, vfc1_b, mfc1_b,
        scale1, bias1f, scale2, bias2f, scale3, bias3f, biasfc);
    prep_convw_k<64><<<288, 256, 0, stream>>>(conv2_w, w2t, planeW2);
    prep_convw_k<128><<<576, 256, 0, stream>>>(conv3_w, w3t, planeW3);
    prep_bigw_k<<<13824, 256, 0, stream>>>(pfc1_w, vfc1_w, mfc1_w, bigw, planeBW);
    prep_selw_k<<<36, 256, 0, stream>>>(mfc1_w, selw);

    __hip_bfloat16* h1s  = (__hip_bfloat16*)A1;
    __hip_bfloat16* h2s  = (__hip_bfloat16*)A2;
    __hip_bfloat16* h3s  = (__hip_bfloat16*)A1;   // overwrites h1s (dead after conv2)
    float*          fpar = (float*)A2;            // overwrites h2s (dead after conv3)

    for (int cchunk = 0; cchunk < NCHUNK; ++cchunk) {
        const int b_base = cchunk * CHUNK;
        conv1_k<<<CHUNK * 36 * 64 / 256, 256, 0, stream>>>(
            x, conv1_w, scale1, bias1f, h1s, planeA1, b_base);
        conv_gemm_k<64><<<CHUNK / 4, 256, 0, stream>>>(
            h1s, planeA1, w2t, planeW2, scale2, bias2f, h2s, planeA2);
        conv_gemm_k<128><<<CHUNK / 4, 256, 0, stream>>>(
            h2s, planeA2, w3t, planeW3, scale3, bias3f, h3s, planeA2);
        fc_partial_k<<<576, 256, 0, stream>>>(h3s, planeA2, bigw, planeBW, fpar);
        heads_k<<<CHUNK, 256, 0, stream>>>(fpar, biasfc,
            pln_g, pln_b, pfc2_w, pfc2_b,
            mln_g, mln_b, mfc2_w, mfc2_b,
            vln_g, vln_b, vfc2_w, vfc2_b,
            selw, (float*)d_out, b_base);
    }
}

// Round 8
// 2022.302 us; speedup vs baseline: 1.2868x; 1.0277x over previous
//
#include <hip/hip_runtime.h>
#include <hip/hip_bf16.h>

#define BQ 8192
#define CHUNK 2048
#define NCHUNK 4
typedef __attribute__((ext_vector_type(8))) __bf16 bf16x8;
typedef __attribute__((ext_vector_type(4))) float f32x4;
typedef __attribute__((ext_vector_type(4))) int int4v;

__device__ __forceinline__ f32x4 mfma16(bf16x8 a, bf16x8 b, f32x4 c) {
    return __builtin_amdgcn_mfma_f32_16x16x32_bf16(a, b, c, 0, 0, 0);
}

// 3-way bf16 split of an fp32 value: v ~= s0+s1+s2 to ~2^-25 rel.
__device__ __forceinline__ void split3(float v, __hip_bfloat16& s0,
                                       __hip_bfloat16& s1, __hip_bfloat16& s2) {
    s0 = __float2bfloat16(v);
    float r = v - __bfloat162float(s0);
    s1 = __float2bfloat16(r);
    r -= __bfloat162float(s1);
    s2 = __float2bfloat16(r);
}

// plane-pair schedule for 6-term fp32-emulated product, grouped by A-plane so
// conv kernels can skip xs re-staging: (a,w) = (0,0),(0,1),(0,2),(1,0),(1,1),(2,0)
__device__ __forceinline__ int pair_a(int pp) { return (0x211000 >> (4 * pp)) & 0xF; }
__device__ __forceinline__ int pair_w(int pp) { return (0x010210 >> (4 * pp)) & 0xF; }

// ---------------- prep kernels ----------------

__global__ void prep_scalars_k(
    const float* __restrict__ c1b, const float* __restrict__ g1,
    const float* __restrict__ b1,  const float* __restrict__ m1,
    const float* __restrict__ v1,
    const float* __restrict__ c2b, const float* __restrict__ g2,
    const float* __restrict__ b2,  const float* __restrict__ m2,
    const float* __restrict__ v2,
    const float* __restrict__ c3b, const float* __restrict__ g3,
    const float* __restrict__ b3,  const float* __restrict__ m3,
    const float* __restrict__ v3,
    const float* __restrict__ pfb, const float* __restrict__ vfb,
    const float* __restrict__ mfb,
    float* __restrict__ scale1, float* __restrict__ bias1f,
    float* __restrict__ scale2, float* __restrict__ bias2f,
    float* __restrict__ scale3, float* __restrict__ bias3f,
    float* __restrict__ biasfc)
{
    int t = threadIdx.x;  // 768 threads
    if (t < 64) {
        float s = g1[t] * rsqrtf(v1[t] + 1e-5f);
        scale1[t] = s;
        bias1f[t] = (c1b[t] - m1[t]) * s + b1[t];
    }
    if (t < 128) {
        float s2 = g2[t] * rsqrtf(v2[t] + 1e-5f);
        scale2[t] = s2;
        bias2f[t] = (c2b[t] - m2[t]) * s2 + b2[t];
        float s3 = g3[t] * rsqrtf(v3[t] + 1e-5f);
        scale3[t] = s3;
        bias3f[t] = (c3b[t] - m3[t]) * s3 + b3[t];
    }
    if (t < 256)      biasfc[t] = pfb[t];
    else if (t < 512) biasfc[t] = vfb[t - 256];
    else              biasfc[t] = mfb[t - 512];
}

// conv weights (O, CIN, 3, 3) fp32 -> 3 bf16 planes in FRAG-MAJOR layout:
// dest = kt*4096 + (n>>5)*1024 + ((n>>4)&1)*512 + (kk>>3)*128 + (n&15)*8 + (kk&7)
// so a wave's B-frag read is base + lane*8 elems (lane-contiguous, conflict-free).
template<int CIN>
__global__ void prep_convw_k(const float* __restrict__ w,
                             __hip_bfloat16* __restrict__ wt, size_t planeW)
{
    int id = blockIdx.x * 256 + threadIdx.x;
    int kk = id & 31;
    int n  = (id >> 5) & 127;
    int kt = id >> 12;
    int k  = kt * 32 + kk;
    int s  = k / CIN;
    int i  = k & (CIN - 1);
    __hip_bfloat16 s0, s1, s2;
    split3(w[(n * CIN + i) * 9 + s], s0, s1, s2);
    size_t dest = (size_t)kt * 4096 + ((n >> 5) * 1024) + (((n >> 4) & 1) * 512)
                + ((kk >> 3) * 128) + ((n & 15) * 8) + (kk & 7);
    wt[dest] = s0; wt[dest + planeW] = s1; wt[dest + 2 * planeW] = s2;
}

// fused FC1 weight -> 3 bf16 planes, frag-major per 128-col group:
// dest = kt*24576 + (n>>7)*4096 + ((n>>6)&1)*2048 + ((n>>4)&3)*512 + (kk>>3)*128 + (n&15)*8 + (kk&7)
// k' = kt*32+kk = p*128+c ; orig k = c*36+p
__global__ void prep_bigw_k(const float* __restrict__ pw,
                            const float* __restrict__ vw,
                            const float* __restrict__ mw,
                            __hip_bfloat16* __restrict__ bigw, size_t planeBW)
{
    int id = blockIdx.x * 256 + threadIdx.x;   // < 4608*768
    int kk = id & 31;
    int n  = (id >> 5) % 768;
    int kt = id / (32 * 768);
    int k2 = kt * 32 + kk;
    int c  = k2 & 127, p = k2 >> 7;
    int k  = c * 36 + p;
    float v;
    if (n < 256)      v = pw[n * 4608 + k];
    else if (n < 512) v = vw[(n - 256) * 4608 + k];
    else              v = mw[(n - 512) * 4644 + k];
    __hip_bfloat16 s0, s1, s2;
    split3(v, s0, s1, s2);
    size_t dest = (size_t)kt * 24576 + ((n >> 7) * 4096) + (((n >> 6) & 1) * 2048)
                + (((n >> 4) & 3) * 512) + ((kk >> 3) * 128) + ((n & 15) * 8) + (kk & 7);
    bigw[dest] = s0; bigw[dest + planeBW] = s1; bigw[dest + 2 * planeBW] = s2;
}

__global__ void prep_selw_k(const float* __restrict__ mw,
                            float* __restrict__ selw)
{
    int j = blockIdx.x, d = threadIdx.x;
    selw[j * 256 + d] = mw[d * 4644 + 4608 + j];
}

// ---------------- conv1 (4->64, K=36): exact fp32 VALU, split-stored ----------------

__global__ __launch_bounds__(256)
void conv1_k(const float* __restrict__ x,               // (B,4,36) full
             const float* __restrict__ w,               // (64,4,9)
             const float* __restrict__ scale, const float* __restrict__ biasf,
             __hip_bfloat16* __restrict__ out, size_t planeA,  // 3 planes (CHUNK,36,64)
             int b_base)
{
    __shared__ float wl[64 * 37];
    int tid = threadIdx.x;
    for (int c = tid; c < 64 * 36; c += 256) {
        int o = c / 36, k = c - o * 36;
        wl[o * 37 + k] = w[c];
    }
    __syncthreads();
    unsigned gid = blockIdx.x * 256 + tid;  // local (chunk) b*36*64 range
    int o = gid & 63;
    unsigned bp = gid >> 6;                 // local b*36+p
    unsigned b = bp / 36;
    int p = bp - b * 36;
    int py = p / 6, px = p - py * 6;
    const float* xb = x + (size_t)(b_base + b) * 4 * 36;
    float acc = 0.f;
#pragma unroll
    for (int i = 0; i < 4; ++i) {
#pragma unroll
        for (int s = 0; s < 9; ++s) {
            int ny = py + s / 3 - 1, nx = px + s % 3 - 1;
            if ((unsigned)ny < 6u && (unsigned)nx < 6u)
                acc += xb[i * 36 + ny * 6 + nx] * wl[o * 37 + i * 9 + s];
        }
    }
    float v = fmaxf(acc * scale[o] + biasf[o], 0.f);
    __hip_bfloat16 s0, s1, s2;
    split3(v, s0, s1, s2);
    size_t idx = (size_t)bp * 64 + o;
    out[idx] = s0; out[idx + planeA] = s1; out[idx + 2 * planeA] = s2;
}

// ---------------- conv2/conv3: implicit-im2col MFMA GEMM, 6-term fp32-emulated ----------------
// Tile: 4 images (144 rows) x 128 cols, wave 144x32, dbuf frag-major weight LDS
// (lane-contiguous reads AND writes -> conflict-free). acc persists over 6
// plane-pairs; xs staged only on A-plane change (3 of 6 passes).
template<int CIN>
__global__ __launch_bounds__(256, 2)
void conv_gemm_k(const __hip_bfloat16* __restrict__ in, size_t planeA,   // 3 planes (CHUNK,36,CIN)
                 const __hip_bfloat16* __restrict__ wt, size_t planeW,   // 3 planes frag-major [K/32][4096]
                 const float* __restrict__ scale,
                 const float* __restrict__ biasf,
                 __hip_bfloat16* __restrict__ out, size_t planeO)        // 3 planes (CHUNK,36,128)
{
    constexpr int PS  = CIN + 8;
    constexpr int CPB = CIN / 32;
    constexpr int NSLICE = CPB * 9;
    constexpr int XS_ELEMS = 144 * PS;
    constexpr int WBUF = 4096;         // elems per weight buffer (frag-major kt slice)
    __shared__ __align__(16) __hip_bfloat16 smem[XS_ELEMS + 2 * WBUF + CIN];
    __hip_bfloat16* xs   = smem;
    __hip_bfloat16* wsld = smem + XS_ELEMS;             // 2 buffers
    __hip_bfloat16* zs   = smem + XS_ELEMS + 2 * WBUF;  // zero region (SAME-pad reads)

    const int tid  = threadIdx.x;
    const int wave = tid >> 6, lane = tid & 63;
    const int m16  = lane & 15, quad = lane >> 4;
    const int b0   = blockIdx.x * 4;   // local image index

    if (tid < CIN) zs[tid] = __float2bfloat16(0.f);

    f32x4 acc[9][2];
#pragma unroll
    for (int i = 0; i < 9; ++i) { acc[i][0] = f32x4{0,0,0,0}; acc[i][1] = f32x4{0,0,0,0}; }

    const int bo0 = wave * 1024 + lane * 8;          // ct=0 frag
    const int bo1 = wave * 1024 + 512 + lane * 8;    // ct=1 frag

    constexpr int CHPP = CIN / 8;
    for (int pp = 0; pp < 6; ++pp) {
        const __hip_bfloat16* inb = in + (size_t)pair_a(pp) * planeA + (size_t)b0 * 36 * CIN;
        const __hip_bfloat16* wP  = wt + (size_t)pair_w(pp) * planeW;
        const bool stage_x = (pp == 0) || (pair_a(pp) != pair_a(pp - 1));

        __syncthreads();   // previous pass finished all LDS reads (covers zs init at pp=0)
        if (stage_x) {
            for (int c = tid; c < 144 * CHPP; c += 256) {
                int pix = c / CHPP;
                int off = (c - pix * CHPP) * 8;
                *(int4v*)(xs + pix * PS + off) = *(const int4v*)(inb + pix * CIN + off);
            }
        }
        {   // stage weight slice kt=0 into buffer 0 (identity copy, lane-contiguous)
            const int4v* g = (const int4v*)wP;
            int4v w0 = g[tid], w1 = g[tid + 256];
            *(int4v*)(wsld + tid * 8) = w0;
            *(int4v*)(wsld + (tid + 256) * 8) = w1;
        }
        __syncthreads();
        int cur = 0;

        for (int s = 0; s < 9; ++s) {
            const int dy = s / 3 - 1, dx = s % 3 - 1;
            int aoff[9];
#pragma unroll
            for (int rt = 0; rt < 9; ++rt) {
                int m   = rt * 16 + m16;          // 0..143
                int img = m / 36;
                int p   = m - img * 36;
                int py  = p / 6, px = p - py * 6;
                int ny  = py + dy, nx = px + dx;
                bool ok = ((unsigned)ny < 6u) && ((unsigned)nx < 6u);
                int base = ok ? ((img * 36 + ny * 6 + nx) * PS) : (XS_ELEMS + 2 * WBUF);
                aoff[rt] = base + quad * 8;
            }
            for (int c = 0; c < CPB; ++c) {
                const int kt = s * CPB + c;
                const bool more = (kt + 1 < NSLICE);
                int4v n0, n1;
                if (more) {  // global->reg prefetch of next weight slice
                    const int4v* g = (const int4v*)(wP + (size_t)(kt + 1) * WBUF);
                    n0 = g[tid]; n1 = g[tid + 256];
                }
                const __hip_bfloat16* wb = wsld + cur * WBUF;
                bf16x8 bf0 = *(const bf16x8*)(wb + bo0);
                bf16x8 bf1 = *(const bf16x8*)(wb + bo1);
                const int coff = c * 32;
#pragma unroll
                for (int rt = 0; rt < 9; ++rt) {
                    bf16x8 af = *(const bf16x8*)(smem + aoff[rt] + coff);
                    acc[rt][0] = mfma16(af, bf0, acc[rt][0]);
                    acc[rt][1] = mfma16(af, bf1, acc[rt][1]);
                }
                if (more) {  // write next slice into alternate buffer (lane-contiguous)
                    __hip_bfloat16* wn = wsld + (cur ^ 1) * WBUF;
                    *(int4v*)(wn + tid * 8) = n0;
                    *(int4v*)(wn + (tid + 256) * 8) = n1;
                }
                __syncthreads();   // single barrier per kt (dbuf)
                cur ^= 1;
            }
        }
    }

    // epilogue: fused BN scale/bias + relu, split-store 3 bf16 planes
#pragma unroll
    for (int ct = 0; ct < 2; ++ct) {
        const int n = wave * 32 + ct * 16 + m16;
        const float sc = scale[n], bi = biasf[n];
#pragma unroll
        for (int rt = 0; rt < 9; ++rt) {
            const int mrow = rt * 16 + quad * 4;
#pragma unroll
            for (int r = 0; r < 4; ++r) {
                float v = fmaxf(acc[rt][ct][r] * sc + bi, 0.f);
                __hip_bfloat16 s0, s1, s2;
                split3(v, s0, s1, s2);
                size_t idx = (size_t)(b0 * 36 + mrow + r) * 128 + n;
                out[idx] = s0; out[idx + planeO] = s1; out[idx + 2 * planeO] = s2;
            }
        }
    }
}

// ---------------- FC1 partial GEMM: one plane-pair per block, dbuf frag-major LDS ----------------
// grid = 6 pp x 6 nblk x 16 mblk = 576 blocks; partial[pp] (CHUNK,768) fp32

__global__ __launch_bounds__(256, 3)
void fc_partial_k(const __hip_bfloat16* __restrict__ A, size_t planeF,    // 3 planes (CHUNK,4608)
                  const __hip_bfloat16* __restrict__ Bw, size_t planeBW,  // 3 planes frag-major [144][24576]
                  float* __restrict__ partial)                            // [6](CHUNK,768)
{
    constexpr int HBUF = 4096;              // as or bs elems (frag-major)
    __shared__ __align__(16) __hip_bfloat16 smem[2 * 2 * HBUF];  // [buf][as|bs]
    const int tid = threadIdx.x, wave = tid >> 6, lane = tid & 63;
    const int m16 = lane & 15, quad = lane >> 4;
    const int mblk = blockIdx.x & 15;
    const int rest = blockIdx.x >> 4;           // 0..35
    const int nblk = rest % 6;
    const int pp   = rest / 6;
    const size_t m0 = (size_t)mblk * 128;
    const int wr = wave >> 1, wc = wave & 1;

    const __hip_bfloat16* Ap = A + (size_t)pair_a(pp) * planeF;
    const __hip_bfloat16* Bp = Bw + (size_t)pair_w(pp) * planeBW + (size_t)nblk * 4096;

    f32x4 acc[4][4];
#pragma unroll
    for (int i = 0; i < 4; ++i)
#pragma unroll
        for (int j = 0; j < 4; ++j) acc[i][j] = f32x4{0,0,0,0};

    const int cr = tid >> 2, co = (tid & 3) * 8;
    // frag-major offsets: reads are base + lane*8 (conflict-free)
    int ao[4], bo[4];
#pragma unroll
    for (int i = 0; i < 4; ++i) {
        ao[i] = wr * 2048 + i * 512 + lane * 8;                 // into as
        bo[i] = HBUF + wc * 2048 + i * 512 + lane * 8;          // into bs
    }
    const int adst = ((cr >> 4) & 3) * 512 + (tid & 3) * 128 + (cr & 15) * 8;

    auto ldA = [&](int kt, int4v& a0, int4v& a1) {
        const __hip_bfloat16* base = Ap + (m0 + cr) * 4608 + kt * 32 + co;
        a0 = *(const int4v*)base;
        a1 = *(const int4v*)(base + (size_t)64 * 4608);
    };
    auto ldB = [&](int kt, int4v& b0, int4v& b1) {
        const int4v* g = (const int4v*)(Bp + (size_t)kt * 24576);
        b0 = g[tid]; b1 = g[tid + 256];
    };
    auto stAB = [&](int buf, int4v a0, int4v a1, int4v b0, int4v b1) {
        __hip_bfloat16* base = smem + buf * 2 * HBUF;
        *(int4v*)(base + adst) = a0;                  // rows 0..63  (wr'=0)
        *(int4v*)(base + 2048 + adst) = a1;           // rows 64..127 (wr'=1)
        *(int4v*)(base + HBUF + tid * 8) = b0;        // identity copy
        *(int4v*)(base + HBUF + (tid + 256) * 8) = b1;
    };

    { int4v a0,a1,b0,b1; ldA(0,a0,a1); ldB(0,b0,b1); stAB(0,a0,a1,b0,b1); }
    __syncthreads();
    int cur = 0;

    for (int kt = 0; kt < 144; ++kt) {
        int4v a0, a1, b0, b1;
        const bool more = (kt < 143);
        if (more) { ldA(kt + 1, a0, a1); ldB(kt + 1, b0, b1); }
        const __hip_bfloat16* base = smem + cur * 2 * HBUF;
        bf16x8 af[4], bf[4];
#pragma unroll
        for (int i = 0; i < 4; ++i) {
            af[i] = *(const bf16x8*)(base + ao[i]);
            bf[i] = *(const bf16x8*)(base + bo[i]);
        }
#pragma unroll
        for (int i = 0; i < 4; ++i)
#pragma unroll
            for (int j = 0; j < 4; ++j)
                acc[i][j] = mfma16(af[i], bf[j], acc[i][j]);
        if (more) { stAB(cur ^ 1, a0, a1, b0, b1); }
        __syncthreads();   // single barrier per kt (dbuf)
        cur ^= 1;
    }

    float* outp = partial + (size_t)pp * CHUNK * 768;
    const int n0 = nblk * 128;
#pragma unroll
    for (int i = 0; i < 4; ++i) {
        const int row = wr * 64 + i * 16 + quad * 4;
#pragma unroll
        for (int j = 0; j < 4; ++j) {
            const int col = n0 + wc * 64 + j * 16 + m16;
#pragma unroll
            for (int r = 0; r < 4; ++r)
                outp[(m0 + row + r) * 768 + col] = acc[i][j][r];
        }
    }
}

// ---------------- heads: partial-sum + LN + small GEMVs + argmax + dueling (fp32) ----------------

__global__ __launch_bounds__(256)
void heads_k(const float* __restrict__ partial,          // [6](CHUNK,768): [piece|value|move]
             const float* __restrict__ biasfc,           // 768
             const float* __restrict__ pln_g, const float* __restrict__ pln_b,
             const float* __restrict__ pfc2_w, const float* __restrict__ pfc2_b,
             const float* __restrict__ mln_g, const float* __restrict__ mln_b,
             const float* __restrict__ mfc2_w, const float* __restrict__ mfc2_b,
             const float* __restrict__ vln_g, const float* __restrict__ vln_b,
             const float* __restrict__ vfc2_w, const float* __restrict__ vfc2_b,
             const float* __restrict__ selw,             // (36,256)
             float* __restrict__ q,                      // (B,1296) full
             int b_base)
{
    __shared__ float hp[256], hv[256], hm[256];
    __shared__ float pl[36], ml[36];
    __shared__ float red[4];
    __shared__ float valv, plm_s, mlm_s;
    __shared__ int amax_s;

    const int tid = threadIdx.x, wave = tid >> 6, lane = tid & 63;
    const size_t b = blockIdx.x;                // local
    const size_t bg = b_base + b;               // global

    // inline fc-reduce: sum 6 partials + bias
    float pp = biasfc[tid], vv = biasfc[256 + tid], mm = biasfc[512 + tid];
#pragma unroll
    for (int k = 0; k < 6; ++k) {
        const float* row = partial + (size_t)k * CHUNK * 768 + b * 768;
        pp += row[tid]; vv += row[256 + tid]; mm += row[512 + tid];
    }

    auto warpSum = [&](float v) {
        v += __shfl_xor(v, 1);  v += __shfl_xor(v, 2);  v += __shfl_xor(v, 4);
        v += __shfl_xor(v, 8);  v += __shfl_xor(v, 16); v += __shfl_xor(v, 32);
        return v;
    };
    auto blockSum = [&](float v) {
        v = warpSum(v);
        if (lane == 0) red[wave] = v;
        __syncthreads();
        float s = red[0] + red[1] + red[2] + red[3];
        __syncthreads();
        return s;
    };
    auto lnrelu = [&](float x, const float* g, const float* bb) {
        float mu  = blockSum(x) * (1.f / 256.f);
        float d   = x - mu;
        float var = blockSum(d * d) * (1.f / 256.f);
        float y   = d * rsqrtf(var + 1e-5f) * g[tid] + bb[tid];
        return fmaxf(y, 0.f);
    };

    hp[tid] = lnrelu(pp, pln_g, pln_b);
    hv[tid] = lnrelu(vv, vln_g, vln_b);
    __syncthreads();

    {
        float h0 = hp[lane], h1 = hp[64 + lane], h2 = hp[128 + lane], h3 = hp[192 + lane];
#pragma unroll
        for (int jj = 0; jj < 9; ++jj) {
            int j = wave * 9 + jj;
            const float* wr_ = pfc2_w + j * 256;
            float s = h0 * wr_[lane] + h1 * wr_[64 + lane]
                    + h2 * wr_[128 + lane] + h3 * wr_[192 + lane];
            s = warpSum(s);
            if (lane == 0) pl[j] = s + pfc2_b[j];
        }
        if (wave == 0) {
            float g0 = hv[lane], g1 = hv[64 + lane], g2 = hv[128 + lane], g3 = hv[192 + lane];
            float s = g0 * vfc2_w[lane] + g1 * vfc2_w[64 + lane]
                    + g2 * vfc2_w[128 + lane] + g3 * vfc2_w[192 + lane];
            s = warpSum(s);
            if (lane == 0) valv = s + vfc2_b[0];
        }
    }
    __syncthreads();
    if (tid == 0) {   // first-max argmax (jnp semantics) + mean
        float m = -1e30f, s = 0.f; int idx = 0;
        for (int j = 0; j < 36; ++j) { float v = pl[j]; s += v; if (v > m) { m = v; idx = j; } }
        plm_s = s * (1.f / 36.f); amax_s = idx;
    }
    __syncthreads();

    mm += selw[amax_s * 256 + tid];   // one-hot concat == single column add
    hm[tid] = lnrelu(mm, mln_g, mln_b);
    __syncthreads();
    {
        float h0 = hm[lane], h1 = hm[64 + lane], h2 = hm[128 + lane], h3 = hm[192 + lane];
#pragma unroll
        for (int jj = 0; jj < 9; ++jj) {
            int j = wave * 9 + jj;
            const float* wr_ = mfc2_w + j * 256;
            float s = h0 * wr_[lane] + h1 * wr_[64 + lane]
                    + h2 * wr_[128 + lane] + h3 * wr_[192 + lane];
            s = warpSum(s);
            if (lane == 0) ml[j] = s + mfc2_b[j];
        }
    }
    __syncthreads();
    if (tid == 0) {
        float s = 0.f;
        for (int j = 0; j < 36; ++j) s += ml[j];
        mlm_s = s * (1.f / 36.f);
    }
    __syncthreads();

    const float val = valv, plm = plm_s, mlm = mlm_s;
    for (int idx = tid; idx < 1296; idx += 256) {
        int i = idx / 36, j = idx - i * 36;
        q[bg * 1296 + idx] = val + (pl[i] - plm) + (ml[j] - mlm);
    }
}

// ---------------- launch ----------------

extern "C" void kernel_launch(void* const* d_in, const int* in_sizes, int n_in,
                              void* d_out, int out_size, void* d_ws, size_t ws_size,
                              hipStream_t stream)
{
    const float* x       = (const float*)d_in[0];
    const float* conv1_w = (const float*)d_in[1];
    const float* conv1_b = (const float*)d_in[2];
    const float* bn1_g   = (const float*)d_in[3];
    const float* bn1_b   = (const float*)d_in[4];
    const float* bn1_m   = (const float*)d_in[5];
    const float* bn1_v   = (const float*)d_in[6];
    const float* conv2_w = (const float*)d_in[7];
    const float* conv2_b = (const float*)d_in[8];
    const float* bn2_g   = (const float*)d_in[9];
    const float* bn2_b   = (const float*)d_in[10];
    const float* bn2_m   = (const float*)d_in[11];
    const float* bn2_v   = (const float*)d_in[12];
    const float* conv3_w = (const float*)d_in[13];
    const float* conv3_b = (const float*)d_in[14];
    const float* bn3_g   = (const float*)d_in[15];
    const float* bn3_b   = (const float*)d_in[16];
    const float* bn3_m   = (const float*)d_in[17];
    const float* bn3_v   = (const float*)d_in[18];
    const float* pfc1_w  = (const float*)d_in[19];
    const float* pfc1_b  = (const float*)d_in[20];
    const float* pln_g   = (const float*)d_in[21];
    const float* pln_b   = (const float*)d_in[22];
    const float* pfc2_w  = (const float*)d_in[23];
    const float* pfc2_b  = (const float*)d_in[24];
    const float* mfc1_w  = (const float*)d_in[25];
    const float* mfc1_b  = (const float*)d_in[26];
    const float* mln_g   = (const float*)d_in[27];
    const float* mln_b   = (const float*)d_in[28];
    const float* mfc2_w  = (const float*)d_in[29];
    const float* mfc2_b  = (const float*)d_in[30];
    const float* vfc1_w  = (const float*)d_in[31];
    const float* vfc1_b  = (const float*)d_in[32];
    const float* vln_g   = (const float*)d_in[33];
    const float* vln_b   = (const float*)d_in[34];
    const float* vfc2_w  = (const float*)d_in[35];
    const float* vfc2_b  = (const float*)d_in[36];

    const size_t planeW2 = 576 * 128;               // conv2 weight plane elems
    const size_t planeW3 = 1152 * 128;              // conv3 weight plane elems
    const size_t planeBW = (size_t)4608 * 768;      // fc weight plane elems
    const size_t planeA1 = (size_t)CHUNK * 36 * 64; // h1 plane elems (per chunk)
    const size_t planeA2 = (size_t)CHUNK * 36 * 128;// h2/h3 plane elems (per chunk)

    char* ws = (char*)d_ws;
    size_t off = 0;
    auto alloc = [&](size_t bytes) -> char* {
        char* p = ws + off; off += (bytes + 255) & ~(size_t)255; return p;
    };
    __hip_bfloat16* w2t  = (__hip_bfloat16*)alloc(3 * planeW2 * 2);
    __hip_bfloat16* w3t  = (__hip_bfloat16*)alloc(3 * planeW3 * 2);
    __hip_bfloat16* bigw = (__hip_bfloat16*)alloc(3 * planeBW * 2);
    float* selw   = (float*)alloc(36 * 256 * 4);
    float* scale1 = (float*)alloc(64 * 4);
    float* bias1f = (float*)alloc(64 * 4);
    float* scale2 = (float*)alloc(128 * 4);
    float* bias2f = (float*)alloc(128 * 4);
    float* scale3 = (float*)alloc(128 * 4);
    float* bias3f = (float*)alloc(128 * 4);
    float* biasfc = (float*)alloc(768 * 4);
    // ping-pong arenas, per-chunk:
    //   A1: h1 (28.3MB) -> h3 (56.6MB)
    //   A2: h2 (56.6MB) -> fc partials (37.75MB)
    char* A1 = alloc(3 * planeA2 * 2);   // 56.6 MB
    char* A2 = alloc(3 * planeA2 * 2);   // 56.6 MB
    // total ws ~136 MB (round-2 proved >=196 MB available; round-3 crash proved <475)

    prep_scalars_k<<<1, 768, 0, stream>>>(
        conv1_b, bn1_g, bn1_b, bn1_m, bn1_v,
        conv2_b, bn2_g, bn2_b, bn2_m, bn2_v,
        conv3_b, bn3_g, bn3_b, bn3_m, bn3_v,
        pfc1_b, vfc1_b, mfc1_b,
        scale1, bias1f, scale2, bias2f, scale3, bias3f, biasfc);
    prep_convw_k<64><<<288, 256, 0, stream>>>(conv2_w, w2t, planeW2);
    prep_convw_k<128><<<576, 256, 0, stream>>>(conv3_w, w3t, planeW3);
    prep_bigw_k<<<13824, 256, 0, stream>>>(pfc1_w, vfc1_w, mfc1_w, bigw, planeBW);
    prep_selw_k<<<36, 256, 0, stream>>>(mfc1_w, selw);

    __hip_bfloat16* h1s  = (__hip_bfloat16*)A1;
    __hip_bfloat16* h2s  = (__hip_bfloat16*)A2;
    __hip_bfloat16* h3s  = (__hip_bfloat16*)A1;   // overwrites h1s (dead after conv2)
    float*          fpar = (float*)A2;            // overwrites h2s (dead after conv3)

    for (int cchunk = 0; cchunk < NCHUNK; ++cchunk) {
        const int b_base = cchunk * CHUNK;
        conv1_k<<<CHUNK * 36 * 64 / 256, 256, 0, stream>>>(
            x, conv1_w, scale1, bias1f, h1s, planeA1, b_base);
        conv_gemm_k<64><<<CHUNK / 4, 256, 0, stream>>>(
            h1s, planeA1, w2t, planeW2, scale2, bias2f, h2s, planeA2);
        conv_gemm_k<128><<<CHUNK / 4, 256, 0, stream>>>(
            h2s, planeA2, w3t, planeW3, scale3, bias3f, h3s, planeA2);
        fc_partial_k<<<576, 256, 0, stream>>>(h3s, planeA2, bigw, planeBW, fpar);
        heads_k<<<CHUNK, 256, 0, stream>>>(fpar, biasfc,
            pln_g, pln_b, pfc2_w, pfc2_b,
            mln_g, mln_b, mfc2_w, mfc2_b,
            vln_g, vln_b, vfc2_w, vfc2_b,
            selw, (float*)d_out, b_base);
    }
}